// Round 10
// baseline (357.750 us; speedup 1.0000x reference)
//
#include <hip/hip_runtime.h>
#include <cmath>

namespace {

constexpr int B_ = 2, T_ = 2048, C_ = 1024, H_ = 16;
constexpr float GAMMA_INV = 0.125f;   // 1/GAMMA
constexpr float SCALE = 0.125f;       // 1/sqrt(D), D=64

typedef __attribute__((ext_vector_type(8))) short bf16x8;
typedef __attribute__((ext_vector_type(4))) float f32x4;
typedef unsigned short ushort_t;

__device__ __forceinline__ ushort_t f2bf(float x) {
  union { float f; unsigned int u; } v; v.f = x;
  unsigned int r = (v.u + 0x7fffu + ((v.u >> 16) & 1u)) >> 16;
  return (ushort_t)r;
}

__device__ __forceinline__ unsigned pk_bf16(float a, float b) {
  unsigned r;
  asm("v_cvt_pk_bf16_f32 %0, %1, %2" : "=v"(r) : "v"(a), "v"(b));
  return r;
}

__device__ __forceinline__ f32x4 mfma16(bf16x8 a, bf16x8 b, f32x4 c) {
  return __builtin_amdgcn_mfma_f32_16x16x32_bf16(a, b, c, 0, 0, 0);
}

// ---------------- bf16 MFMA GEMM, register-staged LDS ----------------
constexpr int GBM = 128, GBN = 128, GBK = 32;
constexpr int LDP = 40;

__global__ __launch_bounds__(256) void gemm_bt(const ushort_t* __restrict__ A,
                                               const ushort_t* __restrict__ Bt,
                                               float* __restrict__ Cm,
                                               int N, int K) {
  __shared__ alignas(16) ushort_t As[GBM][LDP];
  __shared__ alignas(16) ushort_t Bs[GBN][LDP];
  const int tid = threadIdx.x;
  const int m0 = blockIdx.y * GBM, n0 = blockIdx.x * GBN;
  const int wv = tid >> 6;
  const int ln = tid & 63;
  const int lr = ln & 15, hi = ln >> 4;
  const int wr = wv >> 1, wc = wv & 1;

  const int sr0 = tid >> 2, sc0 = (tid & 3) * 8;
  const int sr1 = sr0 + 64;
  const ushort_t* gA0 = A + (size_t)(m0 + sr0) * K + sc0;
  const ushort_t* gA1 = A + (size_t)(m0 + sr1) * K + sc0;
  const ushort_t* gB0 = Bt + (size_t)(n0 + sr0) * K + sc0;
  const ushort_t* gB1 = Bt + (size_t)(n0 + sr1) * K + sc0;

  f32x4 acc[4][4];
  #pragma unroll
  for (int m = 0; m < 4; ++m)
    #pragma unroll
    for (int n = 0; n < 4; ++n)
      #pragma unroll
      for (int r = 0; r < 4; ++r) acc[m][n][r] = 0.0f;

  for (int k0 = 0; k0 < K; k0 += GBK) {
    uint4 a0 = *(const uint4*)(gA0 + k0);
    uint4 a1 = *(const uint4*)(gA1 + k0);
    uint4 b0 = *(const uint4*)(gB0 + k0);
    uint4 b1 = *(const uint4*)(gB1 + k0);
    *(uint4*)&As[sr0][sc0] = a0;
    *(uint4*)&As[sr1][sc0] = a1;
    *(uint4*)&Bs[sr0][sc0] = b0;
    *(uint4*)&Bs[sr1][sc0] = b1;
    __syncthreads();
    bf16x8 af[4], bfr[4];
    #pragma unroll
    for (int m = 0; m < 4; ++m)
      af[m] = *(const bf16x8*)&As[wr * 64 + m * 16 + lr][hi * 8];
    #pragma unroll
    for (int n = 0; n < 4; ++n)
      bfr[n] = *(const bf16x8*)&Bs[wc * 64 + n * 16 + lr][hi * 8];
    #pragma unroll
    for (int m = 0; m < 4; ++m)
      #pragma unroll
      for (int n = 0; n < 4; ++n)
        acc[m][n] = mfma16(af[m], bfr[n], acc[m][n]);
    __syncthreads();
  }
  #pragma unroll
  for (int m = 0; m < 4; ++m) {
    #pragma unroll
    for (int r = 0; r < 4; ++r) {
      const int row = m0 + wr * 64 + m * 16 + hi * 4 + r;
      float* Crow = Cm + (size_t)row * N + n0 + wc * 64;
      #pragma unroll
      for (int n = 0; n < 4; ++n)
        Crow[n * 16 + lr] = acc[m][n][r];
    }
  }
}

// -------- fp32 -> bf16 convert --------
__global__ __launch_bounds__(256) void f32_to_bf16(const float* __restrict__ in,
                                                   ushort_t* __restrict__ out) {
  const int i = (blockIdx.x * 256 + threadIdx.x) * 4;
  float4 a = *(const float4*)&in[i];
  uint2 p;
  p.x = (unsigned)f2bf(a.x) | ((unsigned)f2bf(a.y) << 16);
  p.y = (unsigned)f2bf(a.z) | ((unsigned)f2bf(a.w) << 16);
  *(uint2*)&out[i] = p;
}

// -------- W (K,N) fp32 -> Wt (N,K) bf16 --------
__global__ __launch_bounds__(256) void wt_bf16(const float* __restrict__ W,
                                               ushort_t* __restrict__ Wt,
                                               int K, int N) {
  __shared__ ushort_t t[32][33];
  const int k0 = blockIdx.y * 32, n0 = blockIdx.x * 32;
  const int i = threadIdx.x;
  const int r = i >> 3, c4 = (i & 7) * 4;
  float4 v = *(const float4*)&W[(size_t)(k0 + r) * N + n0 + c4];
  t[r][c4 + 0] = f2bf(v.x); t[r][c4 + 1] = f2bf(v.y);
  t[r][c4 + 2] = f2bf(v.z); t[r][c4 + 3] = f2bf(v.w);
  __syncthreads();
  ushort_t o0 = t[c4 + 0][r], o1 = t[c4 + 1][r], o2 = t[c4 + 2][r], o3 = t[c4 + 3][r];
  uint2 p;
  p.x = (unsigned)o0 | ((unsigned)o1 << 16);
  p.y = (unsigned)o2 | ((unsigned)o3 << 16);
  *(uint2*)&Wt[(size_t)(n0 + r) * K + k0 + c4] = p;
}

// -------- transform: raw (B,T,2C) fp32 -> packed (B,H,T,128) bf16 --------
__global__ __launch_bounds__(256) void qk_transform(const float* __restrict__ raw,
                                                    ushort_t* __restrict__ out) {
  const int idx = blockIdx.x * 256 + threadIdx.x;
  const int c = idx & (C_ - 1);
  const int bt = idx >> 10;
  const int t = bt & (T_ - 1);
  const int b = bt >> 11;
  const int h = c >> 6, d = c & 63;
  float amp = raw[(size_t)bt * 2048 + c];
  float ph  = raw[(size_t)bt * 2048 + 1024 + c];
  float sp = (amp > 20.f) ? amp : log1pf(expf(amp));
  float qc = sp * cosf(ph);
  float qs = sp * sinf(ph);
  size_t o = ((size_t)((b * H_ + h) * T_ + t)) * 128 + d;
  out[o] = f2bf(qc);
  out[o + 64] = f2bf(qs);
}

// -------- V (B,T,C) fp32 -> V^T (B,H,64,T) bf16 --------
__global__ __launch_bounds__(256) void v_transpose(const float* __restrict__ V,
                                                   ushort_t* __restrict__ VT) {
  const int bh = blockIdx.y;
  const int b = bh >> 4, h = bh & 15;
  const int t0 = blockIdx.x * 32;
  __shared__ ushort_t lds[32][72];
  const int i = threadIdx.x;
  {
    int r = i >> 3, d0 = (i & 7) * 8;
    const float* src = V + ((size_t)(b * T_) + t0 + r) * C_ + h * 64 + d0;
    float4 a = *(const float4*)src;
    float4 c = *(const float4*)(src + 4);
    lds[r][d0 + 0] = f2bf(a.x); lds[r][d0 + 1] = f2bf(a.y);
    lds[r][d0 + 2] = f2bf(a.z); lds[r][d0 + 3] = f2bf(a.w);
    lds[r][d0 + 4] = f2bf(c.x); lds[r][d0 + 5] = f2bf(c.y);
    lds[r][d0 + 6] = f2bf(c.z); lds[r][d0 + 7] = f2bf(c.w);
  }
  __syncthreads();
  {
    int d = i >> 2, tq = (i & 3) * 8;
    ushort_t tmp[8];
    #pragma unroll
    for (int j = 0; j < 8; ++j) tmp[j] = lds[tq + j][d];
    ulonglong2 pk;
    pk.x = (unsigned long long)tmp[0] | ((unsigned long long)tmp[1] << 16) |
           ((unsigned long long)tmp[2] << 32) | ((unsigned long long)tmp[3] << 48);
    pk.y = (unsigned long long)tmp[4] | ((unsigned long long)tmp[5] << 16) |
           ((unsigned long long)tmp[6] << 32) | ((unsigned long long)tmp[7] << 48);
    *(ulonglong2*)(VT + ((size_t)bh * 64 + d) * T_ + t0 + tq) = pk;
  }
}

// -------- flash attention: pair-balanced blocks, k-strip wave parallelism --------
// Q,K: (B*H, T, 128) bf16; VT: (B*H, 64, T) bf16; O: (B,T,C) bf16
// grid 1024: xcd=id&7, g=id>>3: bh=xcd*4+(g&3), pair=g>>2 (0..31).
// Block processes q-tiles qb=63-pair then qa=pair (equal total work ~33 k-tiles).
__global__ __launch_bounds__(256) void attn_mfma(const ushort_t* __restrict__ Q,
                                                 const ushort_t* __restrict__ K,
                                                 const ushort_t* __restrict__ VT,
                                                 const float* __restrict__ theta,
                                                 ushort_t* __restrict__ O) {
  const int id = blockIdx.x;
  const int xcd = id & 7, g = id >> 3;
  const int bh = xcd * 4 + (g & 3);
  const int pair = g >> 2;
  const int b = bh >> 4, h = bh & 15;
  const int tid = threadIdx.x;
  const int w = tid >> 6, lane = tid & 63;
  const int lr = lane & 15, lg = lane >> 4;

  __shared__ float Ocomb[4][32][66];
  __shared__ float mlb[4][2][32];

  const float th = theta[h];
  const ushort_t* Kbh = K + (size_t)bh * T_ * 128;
  const ushort_t* Vbh = VT + (size_t)bh * 64 * T_;
  const float cd = cosf(th * 32.0f), sd = sinf(th * 32.0f);   // +256 keys
  const float c2 = cosf(th * 2.0f), s2 = sinf(th * 2.0f);

  #pragma unroll 1
  for (int half = 0; half < 2; ++half) {
    const int qt = half ? pair : (63 - pair);
    const int q_base = qt * 32;
    const int q_lo = q_base + lr;
    const int q_hi = q_lo + 16;

    // Q B-fragments
    bf16x8 qfl[4], qfh[4];
    {
      const ushort_t* Qrow = Q + ((size_t)bh * T_ + q_lo) * 128 + lg * 8;
      #pragma unroll
      for (int ks = 0; ks < 4; ++ks) {
        qfl[ks] = *(const bf16x8*)(Qrow + ks * 32);
        qfh[ks] = *(const bf16x8*)(Qrow + 16 * 128 + ks * 32);
      }
    }

    // gate rank-2 trig
    const float cql = cosf(th * (float)q_lo * GAMMA_INV) * SCALE;
    const float sql = sinf(th * (float)q_lo * GAMMA_INV) * SCALE;
    const float cqh = cosf(th * (float)q_hi * GAMMA_INV) * SCALE;
    const float sqh = sinf(th * (float)q_hi * GAMMA_INV) * SCALE;
    float ck[4], sk[4];
    #pragma unroll
    for (int r = 0; r < 4; ++r) {
      float ang = th * (float)(w * 64 + lg * 4 + r) * GAMMA_INV;
      ck[r] = cosf(ang); sk[r] = sinf(ang);
    }
    float Ajl[4], Bjl[4], Ajh[4], Bjh[4];
    {
      float cj = 1.0f, sj = 0.0f;
      #pragma unroll
      for (int j = 0; j < 4; ++j) {
        Ajl[j] = cql * cj + sql * sj;
        Bjl[j] = sql * cj - cql * sj;
        Ajh[j] = cqh * cj + sqh * sj;
        Bjh[j] = sqh * cj - cqh * sj;
        float t0 = cj * c2 - sj * s2;
        sj = sj * c2 + cj * s2;
        cj = t0;
      }
    }

    f32x4 o_lo[4], o_hi[4];
    #pragma unroll
    for (int n = 0; n < 4; ++n)
      #pragma unroll
      for (int r = 0; r < 4; ++r) { o_lo[n][r] = 0.0f; o_hi[n][r] = 0.0f; }
    float m_lo = -1e30f, l_lo = 0.0f, m_hi = -1e30f, l_hi = 0.0f;

    const int nkt = (q_base + 95) >> 6;

    for (int t = w; t < nkt; t += 4) {
      const int k0 = t * 64;
      // ---- S = K @ Q^T ----
      f32x4 sl[4], sh[4];
      #pragma unroll
      for (int j = 0; j < 4; ++j)
        #pragma unroll
        for (int r = 0; r < 4; ++r) { sl[j][r] = 0.0f; sh[j][r] = 0.0f; }
      __builtin_amdgcn_s_setprio(1);
      #pragma unroll
      for (int j = 0; j < 4; ++j) {
        const ushort_t* Kr = Kbh + (size_t)(k0 + j * 16 + lr) * 128 + lg * 8;
        #pragma unroll
        for (int ks = 0; ks < 4; ++ks) {
          bf16x8 kf = *(const bf16x8*)(Kr + ks * 32);
          sl[j] = mfma16(kf, qfl[ks], sl[j]);
          sh[j] = mfma16(kf, qfh[ks], sh[j]);
        }
      }
      __builtin_amdgcn_s_setprio(0);
      // ---- gate (+ mask only on boundary tiles: uniform branch) ----
      float vl[4][4], vh[4][4];
      if (k0 + 64 <= q_base) {   // interior: no mask needed
        #pragma unroll
        for (int j = 0; j < 4; ++j)
          #pragma unroll
          for (int r = 0; r < 4; ++r) {
            vl[j][r] = sl[j][r] * (Ajl[j] * ck[r] + Bjl[j] * sk[r]);
            vh[j][r] = sh[j][r] * (Ajh[j] * ck[r] + Bjh[j] * sk[r]);
          }
      } else {
        #pragma unroll
        for (int j = 0; j < 4; ++j)
          #pragma unroll
          for (int r = 0; r < 4; ++r) {
            const int kk = k0 + j * 16 + lg * 4 + r;
            float xl = sl[j][r] * (Ajl[j] * ck[r] + Bjl[j] * sk[r]);
            float xh = sh[j][r] * (Ajh[j] * ck[r] + Bjh[j] * sk[r]);
            vl[j][r] = (kk > q_lo) ? -1e30f : xl;
            vh[j][r] = (kk > q_hi) ? -1e30f : xh;
          }
      }
      // ---- row max ----
      float tml = fmaxf(fmaxf(fmaxf(vl[0][0], vl[0][1]), fmaxf(vl[0][2], vl[0][3])),
                        fmaxf(fmaxf(vl[1][0], vl[1][1]), fmaxf(vl[1][2], vl[1][3])));
      tml = fmaxf(tml, fmaxf(fmaxf(fmaxf(vl[2][0], vl[2][1]), fmaxf(vl[2][2], vl[2][3])),
                             fmaxf(fmaxf(vl[3][0], vl[3][1]), fmaxf(vl[3][2], vl[3][3]))));
      float tmh = fmaxf(fmaxf(fmaxf(vh[0][0], vh[0][1]), fmaxf(vh[0][2], vh[0][3])),
                        fmaxf(fmaxf(vh[1][0], vh[1][1]), fmaxf(vh[1][2], vh[1][3])));
      tmh = fmaxf(tmh, fmaxf(fmaxf(fmaxf(vh[2][0], vh[2][1]), fmaxf(vh[2][2], vh[2][3])),
                             fmaxf(fmaxf(vh[3][0], vh[3][1]), fmaxf(vh[3][2], vh[3][3]))));
      tml = fmaxf(tml, __shfl_xor(tml, 16));
      tml = fmaxf(tml, __shfl_xor(tml, 32));
      tmh = fmaxf(tmh, __shfl_xor(tmh, 16));
      tmh = fmaxf(tmh, __shfl_xor(tmh, 32));
      // ---- defer-max rescale (rare) ----
      if (__ballot(tml > m_lo + 8.0f || tmh > m_hi + 8.0f)) {
        float mnl = fmaxf(m_lo, tml), mnh = fmaxf(m_hi, tmh);
        float el = __expf(m_lo - mnl), eh = __expf(m_hi - mnh);
        m_lo = mnl; m_hi = mnh;
        l_lo *= el; l_hi *= eh;
        #pragma unroll
        for (int r = 0; r < 4; ++r) {
          float erl = __shfl(el, lg * 4 + r);
          float erh = __shfl(eh, lg * 4 + r);
          #pragma unroll
          for (int n = 0; n < 4; ++n) { o_lo[n][r] *= erl; o_hi[n][r] *= erh; }
        }
      }
      // ---- exp + row sum ----
      float el[4][4], eh[4][4], psl = 0.0f, psh = 0.0f;
      #pragma unroll
      for (int j = 0; j < 4; ++j)
        #pragma unroll
        for (int r = 0; r < 4; ++r) {
          el[j][r] = __expf(vl[j][r] - m_lo);
          eh[j][r] = __expf(vh[j][r] - m_hi);
          psl += el[j][r];
          psh += eh[j][r];
        }
      psl += __shfl_xor(psl, 16);
      psl += __shfl_xor(psl, 32);
      psh += __shfl_xor(psh, 16);
      psh += __shfl_xor(psh, 32);
      l_lo += psl; l_hi += psh;
      // ---- pack P ----
      bf16x8 pal[2], pah[2];
      #pragma unroll
      for (int hh = 0; hh < 2; ++hh) {
        union { bf16x8 v8; unsigned u[4]; } ul, uh;
        ul.u[0] = pk_bf16(el[2 * hh][0], el[2 * hh][1]);
        ul.u[1] = pk_bf16(el[2 * hh][2], el[2 * hh][3]);
        ul.u[2] = pk_bf16(el[2 * hh + 1][0], el[2 * hh + 1][1]);
        ul.u[3] = pk_bf16(el[2 * hh + 1][2], el[2 * hh + 1][3]);
        uh.u[0] = pk_bf16(eh[2 * hh][0], eh[2 * hh][1]);
        uh.u[1] = pk_bf16(eh[2 * hh][2], eh[2 * hh][3]);
        uh.u[2] = pk_bf16(eh[2 * hh + 1][0], eh[2 * hh + 1][1]);
        uh.u[3] = pk_bf16(eh[2 * hh + 1][2], eh[2 * hh + 1][3]);
        pal[hh] = ul.v8; pah[hh] = uh.v8;
      }
      // ---- PV direct from global ----
      __builtin_amdgcn_s_setprio(1);
      #pragma unroll
      for (int n = 0; n < 4; ++n) {
        const ushort_t* vr = Vbh + (size_t)(n * 16 + lr) * T_ + k0;
        #pragma unroll
        for (int hh = 0; hh < 2; ++hh) {
          union { bf16x8 v8; uint2 u[2]; } uu;
          uu.u[0] = *(const uint2*)(vr + hh * 32 + lg * 4);
          uu.u[1] = *(const uint2*)(vr + hh * 32 + 16 + lg * 4);
          o_lo[n] = mfma16(pal[hh], uu.v8, o_lo[n]);
          o_hi[n] = mfma16(pah[hh], uu.v8, o_hi[n]);
        }
      }
      __builtin_amdgcn_s_setprio(0);
      // ---- advance key trig by 256 keys ----
      #pragma unroll
      for (int r = 0; r < 4; ++r) {
        float t0 = ck[r] * cd - sk[r] * sd;
        sk[r] = sk[r] * cd + ck[r] * sd;
        ck[r] = t0;
      }
    }

    // ---- combine partials across waves ----
    __syncthreads();   // also guards Ocomb reuse from previous half
    #pragma unroll
    for (int n = 0; n < 4; ++n)
      #pragma unroll
      for (int r = 0; r < 4; ++r) {
        Ocomb[w][lg * 4 + r][n * 16 + lr] = o_lo[n][r];
        Ocomb[w][16 + lg * 4 + r][n * 16 + lr] = o_hi[n][r];
      }
    if (lg == 0) {
      mlb[w][0][lr] = m_lo;  mlb[w][1][lr] = l_lo;
      mlb[w][0][16 + lr] = m_hi;  mlb[w][1][16 + lr] = l_hi;
    }
    __syncthreads();
    {
      const int rr = tid >> 3, dg = (tid & 7) * 8;
      float m0 = mlb[0][0][rr], m1 = mlb[1][0][rr], m2 = mlb[2][0][rr], m3 = mlb[3][0][rr];
      float M = fmaxf(fmaxf(m0, m1), fmaxf(m2, m3));
      float w0 = __expf(m0 - M), w1 = __expf(m1 - M), w2 = __expf(m2 - M), w3 = __expf(m3 - M);
      float l = w0 * mlb[0][1][rr] + w1 * mlb[1][1][rr] + w2 * mlb[2][1][rr] + w3 * mlb[3][1][rr];
      const float inv = 1.0f / l;
      float o[8];
      #pragma unroll
      for (int i = 0; i < 8; ++i) {
        o[i] = (w0 * Ocomb[0][rr][dg + i] + w1 * Ocomb[1][rr][dg + i] +
                w2 * Ocomb[2][rr][dg + i] + w3 * Ocomb[3][rr][dg + i]) * inv;
      }
      uint4 pk;
      pk.x = (unsigned)f2bf(o[0]) | ((unsigned)f2bf(o[1]) << 16);
      pk.y = (unsigned)f2bf(o[2]) | ((unsigned)f2bf(o[3]) << 16);
      pk.z = (unsigned)f2bf(o[4]) | ((unsigned)f2bf(o[5]) << 16);
      pk.w = (unsigned)f2bf(o[6]) | ((unsigned)f2bf(o[7]) << 16);
      const int q = q_base + rr;
      *(uint4*)(O + ((size_t)b * T_ + q) * C_ + h * 64 + dg) = pk;
    }
  }
}

} // namespace

extern "C" void kernel_launch(void* const* d_in, const int* in_sizes, int n_in,
                              void* d_out, int out_size, void* d_ws, size_t ws_size,
                              hipStream_t stream) {
  const float* x  = (const float*)d_in[0];
  const float* Wq = (const float*)d_in[1];
  const float* Wk = (const float*)d_in[2];
  const float* Wv = (const float*)d_in[3];
  const float* Wo = (const float*)d_in[4];
  const float* th = (const float*)d_in[5];
  float* out = (float*)d_out;
  float* ws = (float*)d_ws;

  // ---- workspace layout (float offsets; total 22,020,096 floats = 88 MB) ----
  float* raw = ws;
  float* Vf  = raw;
  ushort_t* Ob  = (ushort_t*)(ws + 4194304);
  ushort_t* vt  = (ushort_t*)(ws + 6291456);
  ushort_t* Qb  = (ushort_t*)(ws + 8388608);
  ushort_t* Kb  = (ushort_t*)(ws + 12582912);
  ushort_t* xb  = (ushort_t*)(ws + 16777216);
  ushort_t* Wqt = (ushort_t*)(ws + 18874368);
  ushort_t* Wkt = (ushort_t*)(ws + 19922944);
  ushort_t* Wvt = (ushort_t*)(ws + 20971520);
  ushort_t* Wot = (ushort_t*)(ws + 21495808);

  dim3 blk(256);
  f32_to_bf16<<<4096, blk, 0, stream>>>(x, xb);
  wt_bf16<<<dim3(64, 32), blk, 0, stream>>>(Wq, Wqt, 1024, 2048);
  wt_bf16<<<dim3(64, 32), blk, 0, stream>>>(Wk, Wkt, 1024, 2048);
  wt_bf16<<<dim3(32, 32), blk, 0, stream>>>(Wv, Wvt, 1024, 1024);
  wt_bf16<<<dim3(32, 32), blk, 0, stream>>>(Wo, Wot, 1024, 1024);

  gemm_bt<<<dim3(16, 32), blk, 0, stream>>>(xb, Wqt, raw, 2048, 1024);
  qk_transform<<<16384, blk, 0, stream>>>(raw, Qb);
  gemm_bt<<<dim3(16, 32), blk, 0, stream>>>(xb, Wkt, raw, 2048, 1024);
  qk_transform<<<16384, blk, 0, stream>>>(raw, Kb);
  gemm_bt<<<dim3(8, 32), blk, 0, stream>>>(xb, Wvt, Vf, 1024, 1024);
  v_transpose<<<dim3(64, 32), blk, 0, stream>>>(Vf, vt);
  attn_mfma<<<1024, blk, 0, stream>>>(Qb, Kb, vt, th, Ob);
  gemm_bt<<<dim3(8, 32), blk, 0, stream>>>(Ob, Wot, out, 1024, 1024);
}

// Round 11
// 276.471 us; speedup vs baseline: 1.2940x; 1.2940x over previous
//
#include <hip/hip_runtime.h>
#include <cmath>

namespace {

constexpr int B_ = 2, T_ = 2048, C_ = 1024, H_ = 16;
constexpr float GAMMA_INV = 0.125f;
constexpr float SCALE = 0.125f;

typedef __attribute__((ext_vector_type(8))) short bf16x8;
typedef __attribute__((ext_vector_type(4))) float f32x4;
typedef unsigned short ushort_t;

__device__ __forceinline__ ushort_t f2bf(float x) {
  union { float f; unsigned int u; } v; v.f = x;
  unsigned int r = (v.u + 0x7fffu + ((v.u >> 16) & 1u)) >> 16;
  return (ushort_t)r;
}

__device__ __forceinline__ unsigned pk_bf16(float a, float b) {
  unsigned r;
  asm("v_cvt_pk_bf16_f32 %0, %1, %2" : "=v"(r) : "v"(a), "v"(b));
  return r;
}

__device__ __forceinline__ f32x4 mfma16(bf16x8 a, bf16x8 b, f32x4 c) {
  return __builtin_amdgcn_mfma_f32_16x16x32_bf16(a, b, c, 0, 0, 0);
}

__device__ __forceinline__ void gld_lds16(const ushort_t* g, ushort_t* l) {
  __builtin_amdgcn_global_load_lds(
      (const __attribute__((address_space(1))) unsigned int*)g,
      (__attribute__((address_space(3))) unsigned int*)l, 16, 0, 0);
}

// ---------------- m97-style GEMM core (global_load_lds staging) ----------------
constexpr int GBM = 128, GBN = 128, GBK = 32;

// fp32-out variant: C = A(M,K)bf16 @ Bt(N,K)^T
__global__ __launch_bounds__(256) void gemm_f32out(const ushort_t* __restrict__ A,
                                                   const ushort_t* __restrict__ Bt,
                                                   float* __restrict__ Cm,
                                                   int N, int K) {
  __shared__ ushort_t As[GBM][GBK];
  __shared__ ushort_t Bs[GBN][GBK];
  const int tid = threadIdx.x;
  const int m0 = blockIdx.y * GBM, n0 = blockIdx.x * GBN;
  const int wv = tid >> 6;
  const int ln = tid & 63;
  const int lr = ln & 15, hi = ln >> 4;
  const int wr = wv >> 1, wc = wv & 1;

  const int r0 = tid >> 2, c8 = (tid & 3) * 8;
  const ushort_t* gA0 = A + (size_t)(m0 + r0) * K + c8;
  const ushort_t* gA1 = A + (size_t)(m0 + 64 + r0) * K + c8;
  const ushort_t* gB0 = Bt + (size_t)(n0 + r0) * K + c8;
  const ushort_t* gB1 = Bt + (size_t)(n0 + 64 + r0) * K + c8;
  ushort_t* lA0 = &As[0][0] + wv * 512;
  ushort_t* lA1 = &As[0][0] + 2048 + wv * 512;
  ushort_t* lB0 = &Bs[0][0] + wv * 512;
  ushort_t* lB1 = &Bs[0][0] + 2048 + wv * 512;

  f32x4 acc[4][4];
  #pragma unroll
  for (int m = 0; m < 4; ++m)
    #pragma unroll
    for (int n = 0; n < 4; ++n)
      #pragma unroll
      for (int r = 0; r < 4; ++r) acc[m][n][r] = 0.0f;

  for (int k0 = 0; k0 < K; k0 += GBK) {
    gld_lds16(gA0 + k0, lA0);
    gld_lds16(gA1 + k0, lA1);
    gld_lds16(gB0 + k0, lB0);
    gld_lds16(gB1 + k0, lB1);
    __syncthreads();
    bf16x8 af[4], bfr[4];
    #pragma unroll
    for (int m = 0; m < 4; ++m)
      af[m] = *(const bf16x8*)&As[wr * 64 + m * 16 + lr][hi * 8];
    #pragma unroll
    for (int n = 0; n < 4; ++n)
      bfr[n] = *(const bf16x8*)&Bs[wc * 64 + n * 16 + lr][hi * 8];
    #pragma unroll
    for (int m = 0; m < 4; ++m)
      #pragma unroll
      for (int n = 0; n < 4; ++n)
        acc[m][n] = mfma16(af[m], bfr[n], acc[m][n]);
    __syncthreads();
  }
  #pragma unroll
  for (int m = 0; m < 4; ++m) {
    #pragma unroll
    for (int r = 0; r < 4; ++r) {
      const int row = m0 + wr * 64 + m * 16 + hi * 4 + r;
      float* Crow = Cm + (size_t)row * N + n0 + wc * 64;
      #pragma unroll
      for (int n = 0; n < 4; ++n)
        Crow[n * 16 + lr] = acc[m][n][r];
    }
  }
}

// fused QK-projection GEMM: A=xb (4096,1024), Bt=Wqkt (4096,1024) interleaved
// [amp,ph] rows; epilogue applies softplus/cos/sin and writes Qb/Kb packed
// (B,H,T,128) bf16 directly.
__global__ __launch_bounds__(256) void gemm_qk(const ushort_t* __restrict__ A,
                                               const ushort_t* __restrict__ Bt,
                                               ushort_t* __restrict__ Qb,
                                               ushort_t* __restrict__ Kb,
                                               int K) {
  __shared__ ushort_t As[GBM][GBK];
  __shared__ ushort_t Bs[GBN][GBK];
  const int tid = threadIdx.x;
  const int m0 = blockIdx.y * GBM, n0 = blockIdx.x * GBN;
  const int wv = tid >> 6;
  const int ln = tid & 63;
  const int lr = ln & 15, hi = ln >> 4;
  const int wr = wv >> 1, wc = wv & 1;

  const int r0 = tid >> 2, c8 = (tid & 3) * 8;
  const ushort_t* gA0 = A + (size_t)(m0 + r0) * K + c8;
  const ushort_t* gA1 = A + (size_t)(m0 + 64 + r0) * K + c8;
  const ushort_t* gB0 = Bt + (size_t)(n0 + r0) * K + c8;
  const ushort_t* gB1 = Bt + (size_t)(n0 + 64 + r0) * K + c8;
  ushort_t* lA0 = &As[0][0] + wv * 512;
  ushort_t* lA1 = &As[0][0] + 2048 + wv * 512;
  ushort_t* lB0 = &Bs[0][0] + wv * 512;
  ushort_t* lB1 = &Bs[0][0] + 2048 + wv * 512;

  f32x4 acc[4][4];
  #pragma unroll
  for (int m = 0; m < 4; ++m)
    #pragma unroll
    for (int n = 0; n < 4; ++n)
      #pragma unroll
      for (int r = 0; r < 4; ++r) acc[m][n][r] = 0.0f;

  for (int k0 = 0; k0 < K; k0 += GBK) {
    gld_lds16(gA0 + k0, lA0);
    gld_lds16(gA1 + k0, lA1);
    gld_lds16(gB0 + k0, lB0);
    gld_lds16(gB1 + k0, lB1);
    __syncthreads();
    bf16x8 af[4], bfr[4];
    #pragma unroll
    for (int m = 0; m < 4; ++m)
      af[m] = *(const bf16x8*)&As[wr * 64 + m * 16 + lr][hi * 8];
    #pragma unroll
    for (int n = 0; n < 4; ++n)
      bfr[n] = *(const bf16x8*)&Bs[wc * 64 + n * 16 + lr][hi * 8];
    #pragma unroll
    for (int m = 0; m < 4; ++m)
      #pragma unroll
      for (int n = 0; n < 4; ++n)
        acc[m][n] = mfma16(af[m], bfr[n], acc[m][n]);
    __syncthreads();
  }
  // ---- fused epilogue: cols interleaved [amp, ph]; lanes lr,lr^1 pair up ----
  const int isK = (n0 >> 11) & 1;          // n0 in [0,2048)=Q, [2048,4096)=K
  ushort_t* Dst = isK ? Kb : Qb;
  const int odd = lr & 1;
  #pragma unroll
  for (int m = 0; m < 4; ++m) {
    #pragma unroll
    for (int r = 0; r < 4; ++r) {
      const int row = m0 + wr * 64 + m * 16 + hi * 4 + r;   // = b*T + t
      #pragma unroll
      for (int n = 0; n < 4; ++n) {
        const int nn = n0 + wc * 64 + n * 16 + lr;
        float x = acc[m][n][r];
        float y = __shfl_xor(x, 1);
        float amp = odd ? y : x;
        float ph  = odd ? x : y;
        float sp = (amp > 20.f) ? amp : __logf(1.0f + __expf(amp));
        float val = sp * (odd ? __sinf(ph) : __cosf(ph));
        const int cc = (nn & 2047) >> 1;
        const int h = cc >> 6, d = cc & 63;
        const int t = row & (T_ - 1), b = row >> 11;
        Dst[(((size_t)(b * H_ + h) * T_) + t) * 128 + d + (odd ? 64 : 0)] = f2bf(val);
      }
    }
  }
}

// -------- fp32 -> bf16 convert --------
__global__ __launch_bounds__(256) void f32_to_bf16(const float* __restrict__ in,
                                                   ushort_t* __restrict__ out) {
  const int i = (blockIdx.x * 256 + threadIdx.x) * 4;
  float4 a = *(const float4*)&in[i];
  uint2 p;
  p.x = (unsigned)f2bf(a.x) | ((unsigned)f2bf(a.y) << 16);
  p.y = (unsigned)f2bf(a.z) | ((unsigned)f2bf(a.w) << 16);
  *(uint2*)&out[i] = p;
}

// -------- W (K,N) fp32 -> Wt (N,K) bf16 --------
__global__ __launch_bounds__(256) void wt_bf16(const float* __restrict__ W,
                                               ushort_t* __restrict__ Wt,
                                               int K, int N) {
  __shared__ ushort_t t[32][33];
  const int k0 = blockIdx.y * 32, n0 = blockIdx.x * 32;
  const int i = threadIdx.x;
  const int r = i >> 3, c4 = (i & 7) * 4;
  float4 v = *(const float4*)&W[(size_t)(k0 + r) * N + n0 + c4];
  t[r][c4 + 0] = f2bf(v.x); t[r][c4 + 1] = f2bf(v.y);
  t[r][c4 + 2] = f2bf(v.z); t[r][c4 + 3] = f2bf(v.w);
  __syncthreads();
  ushort_t o0 = t[c4 + 0][r], o1 = t[c4 + 1][r], o2 = t[c4 + 2][r], o3 = t[c4 + 3][r];
  uint2 p;
  p.x = (unsigned)o0 | ((unsigned)o1 << 16);
  p.y = (unsigned)o2 | ((unsigned)o3 << 16);
  *(uint2*)&Wt[(size_t)(n0 + r) * K + k0 + c4] = p;
}

// -------- Wq/Wk (1024,2048) fp32 -> Wqkt (4096,1024) bf16, [amp,ph] interleaved --------
// out row n' (<2048 from Wq, else Wk): c=(n'&2047)>>1, p=n'&1; src col = c + p*1024.
__global__ __launch_bounds__(256) void wt_qk(const float* __restrict__ Wq,
                                             const float* __restrict__ Wk,
                                             ushort_t* __restrict__ Wqkt) {
  __shared__ float t[32][33];
  const int k0 = blockIdx.x * 32, n0 = blockIdx.y * 32;
  const float* src = (n0 < 2048) ? Wq : Wk;
  const int c0 = (n0 & 2047) >> 1;
  const int i = threadIdx.x;
  {
    const int r = i >> 3, c4 = (i & 7) * 4;   // c4 0..28
    const int scol = (c4 < 16) ? (c0 + c4) : (1024 + c0 + c4 - 16);
    float4 v = *(const float4*)&src[(size_t)(k0 + r) * 2048 + scol];
    t[r][c4 + 0] = v.x; t[r][c4 + 1] = v.y; t[r][c4 + 2] = v.z; t[r][c4 + 3] = v.w;
  }
  __syncthreads();
  {
    const int orow = i >> 3, k4 = (i & 7) * 4;
    const int sel = (orow >> 1) + ((orow & 1) ? 16 : 0);
    uint2 p;
    p.x = (unsigned)f2bf(t[k4 + 0][sel]) | ((unsigned)f2bf(t[k4 + 1][sel]) << 16);
    p.y = (unsigned)f2bf(t[k4 + 2][sel]) | ((unsigned)f2bf(t[k4 + 3][sel]) << 16);
    *(uint2*)&Wqkt[(size_t)(n0 + orow) * 1024 + k0 + k4] = p;
  }
}

// -------- V (B,T,C) fp32 -> V^T (B,H,64,T) bf16 --------
__global__ __launch_bounds__(256) void v_transpose(const float* __restrict__ V,
                                                   ushort_t* __restrict__ VT) {
  const int bh = blockIdx.y;
  const int b = bh >> 4, h = bh & 15;
  const int t0 = blockIdx.x * 32;
  __shared__ ushort_t lds[32][72];
  const int i = threadIdx.x;
  {
    int r = i >> 3, d0 = (i & 7) * 8;
    const float* src = V + ((size_t)(b * T_) + t0 + r) * C_ + h * 64 + d0;
    float4 a = *(const float4*)src;
    float4 c = *(const float4*)(src + 4);
    lds[r][d0 + 0] = f2bf(a.x); lds[r][d0 + 1] = f2bf(a.y);
    lds[r][d0 + 2] = f2bf(a.z); lds[r][d0 + 3] = f2bf(a.w);
    lds[r][d0 + 4] = f2bf(c.x); lds[r][d0 + 5] = f2bf(c.y);
    lds[r][d0 + 6] = f2bf(c.z); lds[r][d0 + 7] = f2bf(c.w);
  }
  __syncthreads();
  {
    int d = i >> 2, tq = (i & 3) * 8;
    ushort_t tmp[8];
    #pragma unroll
    for (int j = 0; j < 8; ++j) tmp[j] = lds[tq + j][d];
    ulonglong2 pk;
    pk.x = (unsigned long long)tmp[0] | ((unsigned long long)tmp[1] << 16) |
           ((unsigned long long)tmp[2] << 32) | ((unsigned long long)tmp[3] << 48);
    pk.y = (unsigned long long)tmp[4] | ((unsigned long long)tmp[5] << 16) |
           ((unsigned long long)tmp[6] << 32) | ((unsigned long long)tmp[7] << 48);
    *(ulonglong2*)(VT + ((size_t)bh * 64 + d) * T_ + t0 + tq) = pk;
  }
}

// -------- flash attention (R8 structure, proven 146us): QBLK=128, LDS dbuf --------
__global__ __launch_bounds__(256) void attn_mfma(const ushort_t* __restrict__ Q,
                                                 const ushort_t* __restrict__ K,
                                                 const ushort_t* __restrict__ VT,
                                                 const float* __restrict__ theta,
                                                 ushort_t* __restrict__ O) {
  const int id = blockIdx.x;
  const int xcd = id & 7, sub = id >> 3;
  const int bh = xcd * 4 + (sub >> 4);
  const int qc = 15 - (sub & 15);
  const int b = bh >> 4, h = bh & 15;
  const int tid = threadIdx.x;
  const int wid = tid >> 6, lane = tid & 63;
  const int q_base = qc * 128 + wid * 32;
  const int lr = lane & 15, lg = lane >> 4;
  const int kx = (lr & 7) << 4;

  __shared__ alignas(16) ushort_t Ksh[2][64 * 128];
  __shared__ alignas(16) ushort_t Vsh[2][64 * 64];

  const float th = theta[h];
  const int q_lo = q_base + lr;
  const int q_hi = q_base + 16 + lr;

  bf16x8 qfl[4], qfh[4];
  {
    const ushort_t* Qrow = Q + ((size_t)bh * T_ + q_lo) * 128 + lg * 8;
    #pragma unroll
    for (int ks = 0; ks < 4; ++ks) {
      qfl[ks] = *(const bf16x8*)(Qrow + ks * 32);
      qfh[ks] = *(const bf16x8*)(Qrow + 16 * 128 + ks * 32);
    }
  }

  const float cql = cosf(th * (float)q_lo * GAMMA_INV) * SCALE;
  const float sql = sinf(th * (float)q_lo * GAMMA_INV) * SCALE;
  const float cqh = cosf(th * (float)q_hi * GAMMA_INV) * SCALE;
  const float sqh = sinf(th * (float)q_hi * GAMMA_INV) * SCALE;
  float ck[4], sk[4];
  #pragma unroll
  for (int r = 0; r < 4; ++r) {
    float ang = th * (float)(lg * 4 + r) * GAMMA_INV;
    ck[r] = cosf(ang); sk[r] = sinf(ang);
  }
  float Ajl[4], Bjl[4], Ajh[4], Bjh[4];
  {
    const float c2 = cosf(th * 2.0f), s2 = sinf(th * 2.0f);
    float cj = 1.0f, sj = 0.0f;
    #pragma unroll
    for (int j = 0; j < 4; ++j) {
      Ajl[j] = cql * cj + sql * sj;
      Bjl[j] = sql * cj - cql * sj;
      Ajh[j] = cqh * cj + sqh * sj;
      Bjh[j] = sqh * cj - cqh * sj;
      float t0 = cj * c2 - sj * s2;
      sj = sj * c2 + cj * s2;
      cj = t0;
    }
  }
  const float cd8 = cosf(th * 8.0f), sd8 = sinf(th * 8.0f);

  f32x4 o_lo[4], o_hi[4];
  #pragma unroll
  for (int n = 0; n < 4; ++n)
    #pragma unroll
    for (int r = 0; r < 4; ++r) { o_lo[n][r] = 0.0f; o_hi[n][r] = 0.0f; }
  float m_lo = -1e30f, l_lo = 0.0f, m_hi = -1e30f, l_hi = 0.0f;

  const int kr = tid >> 2;
  const int kce = (tid & 3) * 32;
  const int vd = tid >> 2;
  const int vce = (tid & 3) * 16;
  const ushort_t* Kgb = K + ((size_t)bh * T_ + kr) * 128 + kce;
  const ushort_t* Vgb = VT + ((size_t)bh * 64 + vd) * T_ + vce;
  uint4 kreg[4], vreg[2];

  const int nkt = 2 * qc + 2;

  {
    #pragma unroll
    for (int c = 0; c < 4; ++c) kreg[c] = *(const uint4*)(Kgb + c * 8);
    #pragma unroll
    for (int c = 0; c < 2; ++c) vreg[c] = *(const uint4*)(Vgb + c * 8);
    #pragma unroll
    for (int c = 0; c < 4; ++c) {
      int byte = (kce * 2 + c * 16) ^ ((kr & 7) << 4);
      *(uint4*)&Ksh[0][kr * 128 + (byte >> 1)] = kreg[c];
    }
    #pragma unroll
    for (int c = 0; c < 2; ++c) {
      int byte = (vce * 2 + c * 16) ^ ((vd & 7) << 4);
      *(uint4*)&Vsh[0][vd * 64 + (byte >> 1)] = vreg[c];
    }
  }
  __syncthreads();

  for (int kt = 0; kt < nkt; ++kt) {
    const int cur = kt & 1;
    const int k0 = kt * 64;
    const bool more = (kt + 1) < nkt;
    if (more) {
      const int koff = (kt + 1) * 64;
      #pragma unroll
      for (int c = 0; c < 4; ++c) kreg[c] = *(const uint4*)(Kgb + (size_t)koff * 128 + c * 8);
      #pragma unroll
      for (int c = 0; c < 2; ++c) vreg[c] = *(const uint4*)(Vgb + koff + c * 8);
    }
    f32x4 sl[4], sh[4];
    #pragma unroll
    for (int j = 0; j < 4; ++j)
      #pragma unroll
      for (int r = 0; r < 4; ++r) { sl[j][r] = 0.0f; sh[j][r] = 0.0f; }
    #pragma unroll
    for (int j = 0; j < 4; ++j) {
      const int rbase = (j * 16 + lr) * 128;
      #pragma unroll
      for (int ks = 0; ks < 4; ++ks) {
        const int byte = (ks * 64 + lg * 16) ^ kx;
        bf16x8 kf = *(const bf16x8*)&Ksh[cur][rbase + (byte >> 1)];
        sl[j] = mfma16(kf, qfl[ks], sl[j]);
        sh[j] = mfma16(kf, qfh[ks], sh[j]);
      }
    }
    float vl[4][4], vh[4][4];
    #pragma unroll
    for (int j = 0; j < 4; ++j)
      #pragma unroll
      for (int r = 0; r < 4; ++r) {
        const int kk = k0 + j * 16 + lg * 4 + r;
        float gl = Ajl[j] * ck[r] + Bjl[j] * sk[r];
        float gh = Ajh[j] * ck[r] + Bjh[j] * sk[r];
        float xl = sl[j][r] * gl;
        float xh = sh[j][r] * gh;
        vl[j][r] = (kk > q_lo) ? -1e30f : xl;
        vh[j][r] = (kk > q_hi) ? -1e30f : xh;
      }
    float tml = vl[0][0], tmh = vh[0][0];
    #pragma unroll
    for (int j = 0; j < 4; ++j)
      #pragma unroll
      for (int r = 0; r < 4; ++r) { tml = fmaxf(tml, vl[j][r]); tmh = fmaxf(tmh, vh[j][r]); }
    tml = fmaxf(tml, __shfl_xor(tml, 16));
    tml = fmaxf(tml, __shfl_xor(tml, 32));
    tmh = fmaxf(tmh, __shfl_xor(tmh, 16));
    tmh = fmaxf(tmh, __shfl_xor(tmh, 32));
    if (__ballot(tml > m_lo + 8.0f || tmh > m_hi + 8.0f)) {
      float mnl = fmaxf(m_lo, tml), mnh = fmaxf(m_hi, tmh);
      float el = __expf(m_lo - mnl), eh = __expf(m_hi - mnh);
      m_lo = mnl; m_hi = mnh;
      l_lo *= el; l_hi *= eh;
      #pragma unroll
      for (int r = 0; r < 4; ++r) {
        float erl = __shfl(el, lg * 4 + r);
        float erh = __shfl(eh, lg * 4 + r);
        #pragma unroll
        for (int n = 0; n < 4; ++n) { o_lo[n][r] *= erl; o_hi[n][r] *= erh; }
      }
    }
    float el[4][4], eh[4][4], psl = 0.0f, psh = 0.0f;
    #pragma unroll
    for (int j = 0; j < 4; ++j)
      #pragma unroll
      for (int r = 0; r < 4; ++r) {
        el[j][r] = __expf(vl[j][r] - m_lo);
        eh[j][r] = __expf(vh[j][r] - m_hi);
        psl += el[j][r];
        psh += eh[j][r];
      }
    psl += __shfl_xor(psl, 16);
    psl += __shfl_xor(psl, 32);
    psh += __shfl_xor(psh, 16);
    psh += __shfl_xor(psh, 32);
    l_lo += psl; l_hi += psh;
    bf16x8 pal[2], pah[2];
    #pragma unroll
    for (int hh = 0; hh < 2; ++hh) {
      union { bf16x8 v8; unsigned u[4]; } ul, uh;
      ul.u[0] = pk_bf16(el[2 * hh][0], el[2 * hh][1]);
      ul.u[1] = pk_bf16(el[2 * hh][2], el[2 * hh][3]);
      ul.u[2] = pk_bf16(el[2 * hh + 1][0], el[2 * hh + 1][1]);
      ul.u[3] = pk_bf16(el[2 * hh + 1][2], el[2 * hh + 1][3]);
      uh.u[0] = pk_bf16(eh[2 * hh][0], eh[2 * hh][1]);
      uh.u[1] = pk_bf16(eh[2 * hh][2], eh[2 * hh][3]);
      uh.u[2] = pk_bf16(eh[2 * hh + 1][0], eh[2 * hh + 1][1]);
      uh.u[3] = pk_bf16(eh[2 * hh + 1][2], eh[2 * hh + 1][3]);
      pal[hh] = ul.v8; pah[hh] = uh.v8;
    }
    #pragma unroll
    for (int n = 0; n < 4; ++n) {
      const int dbase = (n * 16 + lr) * 64;
      #pragma unroll
      for (int hh = 0; hh < 2; ++hh) {
        const int b0 = (hh * 64 + lg * 8) ^ kx;
        const int b1 = (hh * 64 + 32 + lg * 8) ^ kx;
        union { bf16x8 v8; uint2 u[2]; } uu;
        uu.u[0] = *(const uint2*)&Vsh[cur][dbase + (b0 >> 1)];
        uu.u[1] = *(const uint2*)&Vsh[cur][dbase + (b1 >> 1)];
        o_lo[n] = mfma16(pal[hh], uu.v8, o_lo[n]);
        o_hi[n] = mfma16(pah[hh], uu.v8, o_hi[n]);
      }
    }
    #pragma unroll
    for (int r = 0; r < 4; ++r) {
      float t0 = ck[r] * cd8 - sk[r] * sd8;
      sk[r] = sk[r] * cd8 + ck[r] * sd8;
      ck[r] = t0;
    }
    __syncthreads();
    if (more) {
      const int nb = cur ^ 1;
      #pragma unroll
      for (int c = 0; c < 4; ++c) {
        int byte = (kce * 2 + c * 16) ^ ((kr & 7) << 4);
        *(uint4*)&Ksh[nb][kr * 128 + (byte >> 1)] = kreg[c];
      }
      #pragma unroll
      for (int c = 0; c < 2; ++c) {
        int byte = (vce * 2 + c * 16) ^ ((vd & 7) << 4);
        *(uint4*)&Vsh[nb][vd * 64 + (byte >> 1)] = vreg[c];
      }
      __syncthreads();
    }
  }
  #pragma unroll
  for (int r = 0; r < 4; ++r) {
    float lql = __shfl(l_lo, lg * 4 + r);
    float lqh = __shfl(l_hi, lg * 4 + r);
    const float invl = 1.0f / lql;
    const float invh = 1.0f / lqh;
    const int q = q_base + lg * 4 + r;
    ushort_t* OrowL = O + ((size_t)b * T_ + q) * C_ + h * 64;
    ushort_t* OrowH = O + ((size_t)b * T_ + q + 16) * C_ + h * 64;
    #pragma unroll
    for (int n = 0; n < 4; ++n) {
      OrowL[n * 16 + lr] = f2bf(o_lo[n][r] * invl);
      OrowH[n * 16 + lr] = f2bf(o_hi[n][r] * invh);
    }
  }
}

} // namespace

extern "C" void kernel_launch(void* const* d_in, const int* in_sizes, int n_in,
                              void* d_out, int out_size, void* d_ws, size_t ws_size,
                              hipStream_t stream) {
  const float* x  = (const float*)d_in[0];
  const float* Wq = (const float*)d_in[1];
  const float* Wk = (const float*)d_in[2];
  const float* Wv = (const float*)d_in[3];
  const float* Wo = (const float*)d_in[4];
  const float* th = (const float*)d_in[5];
  float* out = (float*)d_out;
  float* ws = (float*)d_ws;

  // ---- workspace (float offsets; 22,020,096 floats = 88 MB, proven size) ----
  float* Vf  = ws;                                   // [0, 4194304) fp32
  ushort_t* Ob   = (ushort_t*)(ws + 4194304);        // 8 MB bf16
  ushort_t* vt   = (ushort_t*)(ws + 6291456);        // 8 MB bf16
  ushort_t* Qb   = (ushort_t*)(ws + 8388608);        // 16 MB bf16
  ushort_t* Kb   = (ushort_t*)(ws + 12582912);       // 16 MB bf16
  ushort_t* xb   = (ushort_t*)(ws + 16777216);       // 8 MB bf16
  ushort_t* Wqkt = (ushort_t*)(ws + 18874368);       // 8 MB bf16 (4096,1024)
  ushort_t* Wvt  = (ushort_t*)(ws + 20971520);       // 2 MB
  ushort_t* Wot  = (ushort_t*)(ws + 21495808);       // 2 MB

  dim3 blk(256);
  f32_to_bf16<<<4096, blk, 0, stream>>>(x, xb);
  wt_qk<<<dim3(32, 128), blk, 0, stream>>>(Wq, Wk, Wqkt);
  wt_bf16<<<dim3(32, 32), blk, 0, stream>>>(Wv, Wvt, 1024, 1024);
  wt_bf16<<<dim3(32, 32), blk, 0, stream>>>(Wo, Wot, 1024, 1024);

  gemm_qk<<<dim3(32, 32), blk, 0, stream>>>(xb, Wqkt, Qb, Kb, 1024);
  gemm_f32out<<<dim3(8, 32), blk, 0, stream>>>(xb, Wvt, Vf, 1024, 1024);
  v_transpose<<<dim3(64, 32), blk, 0, stream>>>(Vf, vt);
  attn_mfma<<<512, blk, 0, stream>>>(Qb, Kb, vt, th, Ob);
  gemm_f32out<<<dim3(8, 32), blk, 0, stream>>>(Ob, Wot, out, 1024, 1024);
}

// Round 13
// 261.262 us; speedup vs baseline: 1.3693x; 1.0582x over previous
//
#include <hip/hip_runtime.h>
#include <cmath>

namespace {

constexpr int B_ = 2, T_ = 2048, C_ = 1024, H_ = 16;
constexpr float GAMMA_INV = 0.125f;
constexpr float SCALE = 0.125f;

typedef __attribute__((ext_vector_type(8))) short bf16x8;
typedef __attribute__((ext_vector_type(4))) float f32x4;
typedef unsigned short ushort_t;

__device__ __forceinline__ ushort_t f2bf(float x) {
  union { float f; unsigned int u; } v; v.f = x;
  unsigned int r = (v.u + 0x7fffu + ((v.u >> 16) & 1u)) >> 16;
  return (ushort_t)r;
}

__device__ __forceinline__ unsigned pk_bf16(float a, float b) {
  unsigned r;
  asm("v_cvt_pk_bf16_f32 %0, %1, %2" : "=v"(r) : "v"(a), "v"(b));
  return r;
}

__device__ __forceinline__ f32x4 mfma16(bf16x8 a, bf16x8 b, f32x4 c) {
  return __builtin_amdgcn_mfma_f32_16x16x32_bf16(a, b, c, 0, 0, 0);
}

__device__ __forceinline__ void gld_lds16(const ushort_t* g, ushort_t* l) {
  __builtin_amdgcn_global_load_lds(
      (const __attribute__((address_space(1))) unsigned int*)g,
      (__attribute__((address_space(3))) unsigned int*)l, 16, 0, 0);
}

// ---------------- m97-style GEMM core (global_load_lds staging) ----------------
constexpr int GBM = 128, GBN = 128, GBK = 32;

__global__ __launch_bounds__(256) void gemm_f32out(const ushort_t* __restrict__ A,
                                                   const ushort_t* __restrict__ Bt,
                                                   float* __restrict__ Cm,
                                                   int N, int K) {
  __shared__ ushort_t As[GBM][GBK];
  __shared__ ushort_t Bs[GBN][GBK];
  const int tid = threadIdx.x;
  const int m0 = blockIdx.y * GBM, n0 = blockIdx.x * GBN;
  const int wv = tid >> 6;
  const int ln = tid & 63;
  const int lr = ln & 15, hi = ln >> 4;
  const int wr = wv >> 1, wc = wv & 1;

  const int r0 = tid >> 2, c8 = (tid & 3) * 8;
  const ushort_t* gA0 = A + (size_t)(m0 + r0) * K + c8;
  const ushort_t* gA1 = A + (size_t)(m0 + 64 + r0) * K + c8;
  const ushort_t* gB0 = Bt + (size_t)(n0 + r0) * K + c8;
  const ushort_t* gB1 = Bt + (size_t)(n0 + 64 + r0) * K + c8;
  ushort_t* lA0 = &As[0][0] + wv * 512;
  ushort_t* lA1 = &As[0][0] + 2048 + wv * 512;
  ushort_t* lB0 = &Bs[0][0] + wv * 512;
  ushort_t* lB1 = &Bs[0][0] + 2048 + wv * 512;

  f32x4 acc[4][4];
  #pragma unroll
  for (int m = 0; m < 4; ++m)
    #pragma unroll
    for (int n = 0; n < 4; ++n)
      #pragma unroll
      for (int r = 0; r < 4; ++r) acc[m][n][r] = 0.0f;

  for (int k0 = 0; k0 < K; k0 += GBK) {
    gld_lds16(gA0 + k0, lA0);
    gld_lds16(gA1 + k0, lA1);
    gld_lds16(gB0 + k0, lB0);
    gld_lds16(gB1 + k0, lB1);
    __syncthreads();
    bf16x8 af[4], bfr[4];
    #pragma unroll
    for (int m = 0; m < 4; ++m)
      af[m] = *(const bf16x8*)&As[wr * 64 + m * 16 + lr][hi * 8];
    #pragma unroll
    for (int n = 0; n < 4; ++n)
      bfr[n] = *(const bf16x8*)&Bs[wc * 64 + n * 16 + lr][hi * 8];
    #pragma unroll
    for (int m = 0; m < 4; ++m)
      #pragma unroll
      for (int n = 0; n < 4; ++n)
        acc[m][n] = mfma16(af[m], bfr[n], acc[m][n]);
    __syncthreads();
  }
  #pragma unroll
  for (int m = 0; m < 4; ++m) {
    #pragma unroll
    for (int r = 0; r < 4; ++r) {
      const int row = m0 + wr * 64 + m * 16 + hi * 4 + r;
      float* Crow = Cm + (size_t)row * N + n0 + wc * 64;
      #pragma unroll
      for (int n = 0; n < 4; ++n)
        Crow[n * 16 + lr] = acc[m][n][r];
    }
  }
}

// fused QK-projection GEMM (R11-proven)
__global__ __launch_bounds__(256) void gemm_qk(const ushort_t* __restrict__ A,
                                               const ushort_t* __restrict__ Bt,
                                               ushort_t* __restrict__ Qb,
                                               ushort_t* __restrict__ Kb,
                                               int K) {
  __shared__ ushort_t As[GBM][GBK];
  __shared__ ushort_t Bs[GBN][GBK];
  const int tid = threadIdx.x;
  const int m0 = blockIdx.y * GBM, n0 = blockIdx.x * GBN;
  const int wv = tid >> 6;
  const int ln = tid & 63;
  const int lr = ln & 15, hi = ln >> 4;
  const int wr = wv >> 1, wc = wv & 1;

  const int r0 = tid >> 2, c8 = (tid & 3) * 8;
  const ushort_t* gA0 = A + (size_t)(m0 + r0) * K + c8;
  const ushort_t* gA1 = A + (size_t)(m0 + 64 + r0) * K + c8;
  const ushort_t* gB0 = Bt + (size_t)(n0 + r0) * K + c8;
  const ushort_t* gB1 = Bt + (size_t)(n0 + 64 + r0) * K + c8;
  ushort_t* lA0 = &As[0][0] + wv * 512;
  ushort_t* lA1 = &As[0][0] + 2048 + wv * 512;
  ushort_t* lB0 = &Bs[0][0] + wv * 512;
  ushort_t* lB1 = &Bs[0][0] + 2048 + wv * 512;

  f32x4 acc[4][4];
  #pragma unroll
  for (int m = 0; m < 4; ++m)
    #pragma unroll
    for (int n = 0; n < 4; ++n)
      #pragma unroll
      for (int r = 0; r < 4; ++r) acc[m][n][r] = 0.0f;

  for (int k0 = 0; k0 < K; k0 += GBK) {
    gld_lds16(gA0 + k0, lA0);
    gld_lds16(gA1 + k0, lA1);
    gld_lds16(gB0 + k0, lB0);
    gld_lds16(gB1 + k0, lB1);
    __syncthreads();
    bf16x8 af[4], bfr[4];
    #pragma unroll
    for (int m = 0; m < 4; ++m)
      af[m] = *(const bf16x8*)&As[wr * 64 + m * 16 + lr][hi * 8];
    #pragma unroll
    for (int n = 0; n < 4; ++n)
      bfr[n] = *(const bf16x8*)&Bs[wc * 64 + n * 16 + lr][hi * 8];
    #pragma unroll
    for (int m = 0; m < 4; ++m)
      #pragma unroll
      for (int n = 0; n < 4; ++n)
        acc[m][n] = mfma16(af[m], bfr[n], acc[m][n]);
    __syncthreads();
  }
  const int isK = (n0 >> 11) & 1;
  ushort_t* Dst = isK ? Kb : Qb;
  const int odd = lr & 1;
  #pragma unroll
  for (int m = 0; m < 4; ++m) {
    #pragma unroll
    for (int r = 0; r < 4; ++r) {
      const int row = m0 + wr * 64 + m * 16 + hi * 4 + r;
      #pragma unroll
      for (int n = 0; n < 4; ++n) {
        const int nn = n0 + wc * 64 + n * 16 + lr;
        float x = acc[m][n][r];
        float y = __shfl_xor(x, 1);
        float amp = odd ? y : x;
        float ph  = odd ? x : y;
        float sp = (amp > 20.f) ? amp : __logf(1.0f + __expf(amp));
        float val = sp * (odd ? __sinf(ph) : __cosf(ph));
        const int cc = (nn & 2047) >> 1;
        const int h = cc >> 6, d = cc & 63;
        const int t = row & (T_ - 1), b = row >> 11;
        Dst[(((size_t)(b * H_ + h) * T_) + t) * 128 + d + (odd ? 64 : 0)] = f2bf(val);
      }
    }
  }
}

// -------- fp32 -> bf16 convert --------
__global__ __launch_bounds__(256) void f32_to_bf16(const float* __restrict__ in,
                                                   ushort_t* __restrict__ out) {
  const int i = (blockIdx.x * 256 + threadIdx.x) * 4;
  float4 a = *(const float4*)&in[i];
  uint2 p;
  p.x = (unsigned)f2bf(a.x) | ((unsigned)f2bf(a.y) << 16);
  p.y = (unsigned)f2bf(a.z) | ((unsigned)f2bf(a.w) << 16);
  *(uint2*)&out[i] = p;
}

// -------- W (K,N) fp32 -> Wt (N,K) bf16 --------
__global__ __launch_bounds__(256) void wt_bf16(const float* __restrict__ W,
                                               ushort_t* __restrict__ Wt,
                                               int K, int N) {
  __shared__ ushort_t t[32][33];
  const int k0 = blockIdx.y * 32, n0 = blockIdx.x * 32;
  const int i = threadIdx.x;
  const int r = i >> 3, c4 = (i & 7) * 4;
  float4 v = *(const float4*)&W[(size_t)(k0 + r) * N + n0 + c4];
  t[r][c4 + 0] = f2bf(v.x); t[r][c4 + 1] = f2bf(v.y);
  t[r][c4 + 2] = f2bf(v.z); t[r][c4 + 3] = f2bf(v.w);
  __syncthreads();
  ushort_t o0 = t[c4 + 0][r], o1 = t[c4 + 1][r], o2 = t[c4 + 2][r], o3 = t[c4 + 3][r];
  uint2 p;
  p.x = (unsigned)o0 | ((unsigned)o1 << 16);
  p.y = (unsigned)o2 | ((unsigned)o3 << 16);
  *(uint2*)&Wt[(size_t)(n0 + r) * K + k0 + c4] = p;
}

// -------- Wq/Wk -> Wqkt interleaved (R11-proven) --------
__global__ __launch_bounds__(256) void wt_qk(const float* __restrict__ Wq,
                                             const float* __restrict__ Wk,
                                             ushort_t* __restrict__ Wqkt) {
  __shared__ float t[32][33];
  const int k0 = blockIdx.x * 32, n0 = blockIdx.y * 32;
  const float* src = (n0 < 2048) ? Wq : Wk;
  const int c0 = (n0 & 2047) >> 1;
  const int i = threadIdx.x;
  {
    const int r = i >> 3, c4 = (i & 7) * 4;
    const int scol = (c4 < 16) ? (c0 + c4) : (1024 + c0 + c4 - 16);
    float4 v = *(const float4*)&src[(size_t)(k0 + r) * 2048 + scol];
    t[r][c4 + 0] = v.x; t[r][c4 + 1] = v.y; t[r][c4 + 2] = v.z; t[r][c4 + 3] = v.w;
  }
  __syncthreads();
  {
    const int orow = i >> 3, k4 = (i & 7) * 4;
    const int sel = (orow >> 1) + ((orow & 1) ? 16 : 0);
    uint2 p;
    p.x = (unsigned)f2bf(t[k4 + 0][sel]) | ((unsigned)f2bf(t[k4 + 1][sel]) << 16);
    p.y = (unsigned)f2bf(t[k4 + 2][sel]) | ((unsigned)f2bf(t[k4 + 3][sel]) << 16);
    *(uint2*)&Wqkt[(size_t)(n0 + orow) * 1024 + k0 + k4] = p;
  }
}

// -------- V (B,T,C) fp32 -> V^T (B,H,64,T) bf16 --------
__global__ __launch_bounds__(256) void v_transpose(const float* __restrict__ V,
                                                   ushort_t* __restrict__ VT) {
  const int bh = blockIdx.y;
  const int b = bh >> 4, h = bh & 15;
  const int t0 = blockIdx.x * 32;
  __shared__ ushort_t lds[32][72];
  const int i = threadIdx.x;
  {
    int r = i >> 3, d0 = (i & 7) * 8;
    const float* src = V + ((size_t)(b * T_) + t0 + r) * C_ + h * 64 + d0;
    float4 a = *(const float4*)src;
    float4 c = *(const float4*)(src + 4);
    lds[r][d0 + 0] = f2bf(a.x); lds[r][d0 + 1] = f2bf(a.y);
    lds[r][d0 + 2] = f2bf(a.z); lds[r][d0 + 3] = f2bf(a.w);
    lds[r][d0 + 4] = f2bf(c.x); lds[r][d0 + 5] = f2bf(c.y);
    lds[r][d0 + 6] = f2bf(c.z); lds[r][d0 + 7] = f2bf(c.w);
  }
  __syncthreads();
  {
    int d = i >> 2, tq = (i & 3) * 8;
    ushort_t tmp[8];
    #pragma unroll
    for (int j = 0; j < 8; ++j) tmp[j] = lds[tq + j][d];
    ulonglong2 pk;
    pk.x = (unsigned long long)tmp[0] | ((unsigned long long)tmp[1] << 16) |
           ((unsigned long long)tmp[2] << 32) | ((unsigned long long)tmp[3] << 48);
    pk.y = (unsigned long long)tmp[4] | ((unsigned long long)tmp[5] << 16) |
           ((unsigned long long)tmp[6] << 32) | ((unsigned long long)tmp[7] << 48);
    *(ulonglong2*)(VT + ((size_t)bh * 64 + d) * T_ + t0 + tq) = pk;
  }
}

// -------- flash attention phase 1: uniform 2-way k-split, fp32 raw partials --------
// grid 1024: xcd=id&7, sub=id>>3 in [0,128): bhl=sub>>5, u=31-(sub&31).
// qt=u>>1, s=u&1, [t0,t1) = [s*(qt+1), (s+1)*(qt+1)). p = bh*32+u.
// Stores RAW O partial (fp32, 128x64 per unit) + per-row (m,l).
__global__ __launch_bounds__(256) void attn_split(const ushort_t* __restrict__ Q,
                                                  const ushort_t* __restrict__ K,
                                                  const ushort_t* __restrict__ VT,
                                                  const float* __restrict__ theta,
                                                  float* __restrict__ Op,
                                                  float* __restrict__ mpart,
                                                  float* __restrict__ lpart) {
  const int id = blockIdx.x;
  const int xcd = id & 7, sub = id >> 3;
  const int bhl = sub >> 5;
  const int u = 31 - (sub & 31);
  const int qt = u >> 1, s = u & 1;
  const int t0 = s * (qt + 1);
  const int t1 = t0 + (qt + 1);
  const int bh = xcd * 4 + bhl;
  const int p = bh * 32 + u;
  float* Op_my = Op + (size_t)p * 8192;

  const int h = bh & 15;
  const int tid = threadIdx.x;
  const int wid = tid >> 6, lane = tid & 63;
  const int q_base = qt * 128 + wid * 32;
  const int lr = lane & 15, lg = lane >> 4;
  const int kx = (lr & 7) << 4;

  __shared__ alignas(16) ushort_t Ksh[2][64 * 128];
  __shared__ alignas(16) ushort_t Vsh[2][64 * 64];

  const float th = theta[h];
  const int q_lo = q_base + lr;
  const int q_hi = q_base + 16 + lr;

  bf16x8 qfl[4], qfh[4];
  {
    const ushort_t* Qrow = Q + ((size_t)bh * T_ + q_lo) * 128 + lg * 8;
    #pragma unroll
    for (int ks = 0; ks < 4; ++ks) {
      qfl[ks] = *(const bf16x8*)(Qrow + ks * 32);
      qfh[ks] = *(const bf16x8*)(Qrow + 16 * 128 + ks * 32);
    }
  }

  const float cql = cosf(th * (float)q_lo * GAMMA_INV) * SCALE;
  const float sql = sinf(th * (float)q_lo * GAMMA_INV) * SCALE;
  const float cqh = cosf(th * (float)q_hi * GAMMA_INV) * SCALE;
  const float sqh = sinf(th * (float)q_hi * GAMMA_INV) * SCALE;
  float ck[4], sk[4];
  #pragma unroll
  for (int r = 0; r < 4; ++r) {
    float ang = th * (float)(t0 * 64 + lg * 4 + r) * GAMMA_INV;
    ck[r] = cosf(ang); sk[r] = sinf(ang);
  }
  float Ajl[4], Bjl[4], Ajh[4], Bjh[4];
  {
    const float c2 = cosf(th * 2.0f), s2 = sinf(th * 2.0f);
    float cj = 1.0f, sj = 0.0f;
    #pragma unroll
    for (int j = 0; j < 4; ++j) {
      Ajl[j] = cql * cj + sql * sj;
      Bjl[j] = sql * cj - cql * sj;
      Ajh[j] = cqh * cj + sqh * sj;
      Bjh[j] = sqh * cj - cqh * sj;
      float t0r = cj * c2 - sj * s2;
      sj = sj * c2 + cj * s2;
      cj = t0r;
    }
  }
  const float cd8 = cosf(th * 8.0f), sd8 = sinf(th * 8.0f);

  f32x4 o_lo[4], o_hi[4];
  #pragma unroll
  for (int n = 0; n < 4; ++n)
    #pragma unroll
    for (int r = 0; r < 4; ++r) { o_lo[n][r] = 0.0f; o_hi[n][r] = 0.0f; }
  float m_lo = -1e30f, l_lo = 0.0f, m_hi = -1e30f, l_hi = 0.0f;

  const int kr = tid >> 2;
  const int kce = (tid & 3) * 32;
  const int vd = tid >> 2;
  const int vce = (tid & 3) * 16;
  const ushort_t* Kgb = K + ((size_t)bh * T_ + kr) * 128 + kce;
  const ushort_t* Vgb = VT + ((size_t)bh * 64 + vd) * T_ + vce;
  uint4 kreg[4], vreg[2];

  // prologue: stage tile t0
  {
    const size_t koff = (size_t)t0 * 64;
    #pragma unroll
    for (int c = 0; c < 4; ++c) kreg[c] = *(const uint4*)(Kgb + koff * 128 + c * 8);
    #pragma unroll
    for (int c = 0; c < 2; ++c) vreg[c] = *(const uint4*)(Vgb + koff + c * 8);
    #pragma unroll
    for (int c = 0; c < 4; ++c) {
      int byte = (kce * 2 + c * 16) ^ ((kr & 7) << 4);
      *(uint4*)&Ksh[0][kr * 128 + (byte >> 1)] = kreg[c];
    }
    #pragma unroll
    for (int c = 0; c < 2; ++c) {
      int byte = (vce * 2 + c * 16) ^ ((vd & 7) << 4);
      *(uint4*)&Vsh[0][vd * 64 + (byte >> 1)] = vreg[c];
    }
  }
  __syncthreads();

  for (int kt = t0; kt < t1; ++kt) {
    const int cur = (kt - t0) & 1;
    const int k0 = kt * 64;
    const bool more = (kt + 1) < t1;
    if (more) {
      const size_t koff = (size_t)(kt + 1) * 64;
      #pragma unroll
      for (int c = 0; c < 4; ++c) kreg[c] = *(const uint4*)(Kgb + koff * 128 + c * 8);
      #pragma unroll
      for (int c = 0; c < 2; ++c) vreg[c] = *(const uint4*)(Vgb + koff + c * 8);
    }
    f32x4 sl[4], sh[4];
    #pragma unroll
    for (int j = 0; j < 4; ++j)
      #pragma unroll
      for (int r = 0; r < 4; ++r) { sl[j][r] = 0.0f; sh[j][r] = 0.0f; }
    #pragma unroll
    for (int j = 0; j < 4; ++j) {
      const int rbase = (j * 16 + lr) * 128;
      #pragma unroll
      for (int ks = 0; ks < 4; ++ks) {
        const int byte = (ks * 64 + lg * 16) ^ kx;
        bf16x8 kf = *(const bf16x8*)&Ksh[cur][rbase + (byte >> 1)];
        sl[j] = mfma16(kf, qfl[ks], sl[j]);
        sh[j] = mfma16(kf, qfh[ks], sh[j]);
      }
    }
    float vl[4][4], vh[4][4];
    #pragma unroll
    for (int j = 0; j < 4; ++j)
      #pragma unroll
      for (int r = 0; r < 4; ++r) {
        const int kk = k0 + j * 16 + lg * 4 + r;
        float gl = Ajl[j] * ck[r] + Bjl[j] * sk[r];
        float gh = Ajh[j] * ck[r] + Bjh[j] * sk[r];
        float xl = sl[j][r] * gl;
        float xh = sh[j][r] * gh;
        vl[j][r] = (kk > q_lo) ? -3e30f : xl;
        vh[j][r] = (kk > q_hi) ? -3e30f : xh;
      }
    float tml = vl[0][0], tmh = vh[0][0];
    #pragma unroll
    for (int j = 0; j < 4; ++j)
      #pragma unroll
      for (int r = 0; r < 4; ++r) { tml = fmaxf(tml, vl[j][r]); tmh = fmaxf(tmh, vh[j][r]); }
    tml = fmaxf(tml, __shfl_xor(tml, 16));
    tml = fmaxf(tml, __shfl_xor(tml, 32));
    tmh = fmaxf(tmh, __shfl_xor(tmh, 16));
    tmh = fmaxf(tmh, __shfl_xor(tmh, 32));
    if (__ballot(tml > m_lo + 8.0f || tmh > m_hi + 8.0f)) {
      float mnl = fmaxf(m_lo, tml), mnh = fmaxf(m_hi, tmh);
      float el = __expf(m_lo - mnl), eh = __expf(m_hi - mnh);
      m_lo = mnl; m_hi = mnh;
      l_lo *= el; l_hi *= eh;
      #pragma unroll
      for (int r = 0; r < 4; ++r) {
        float erl = __shfl(el, lg * 4 + r);
        float erh = __shfl(eh, lg * 4 + r);
        #pragma unroll
        for (int n = 0; n < 4; ++n) { o_lo[n][r] *= erl; o_hi[n][r] *= erh; }
      }
    }
    float el[4][4], eh[4][4], psl = 0.0f, psh = 0.0f;
    #pragma unroll
    for (int j = 0; j < 4; ++j)
      #pragma unroll
      for (int r = 0; r < 4; ++r) {
        el[j][r] = __expf(vl[j][r] - m_lo);
        eh[j][r] = __expf(vh[j][r] - m_hi);
        psl += el[j][r];
        psh += eh[j][r];
      }
    psl += __shfl_xor(psl, 16);
    psl += __shfl_xor(psl, 32);
    psh += __shfl_xor(psh, 16);
    psh += __shfl_xor(psh, 32);
    l_lo += psl; l_hi += psh;
    bf16x8 pal[2], pah[2];
    #pragma unroll
    for (int hh = 0; hh < 2; ++hh) {
      union { bf16x8 v8; unsigned u4[4]; } ul, uh;
      ul.u4[0] = pk_bf16(el[2 * hh][0], el[2 * hh][1]);
      ul.u4[1] = pk_bf16(el[2 * hh][2], el[2 * hh][3]);
      ul.u4[2] = pk_bf16(el[2 * hh + 1][0], el[2 * hh + 1][1]);
      ul.u4[3] = pk_bf16(el[2 * hh + 1][2], el[2 * hh + 1][3]);
      uh.u4[0] = pk_bf16(eh[2 * hh][0], eh[2 * hh][1]);
      uh.u4[1] = pk_bf16(eh[2 * hh][2], eh[2 * hh][3]);
      uh.u4[2] = pk_bf16(eh[2 * hh + 1][0], eh[2 * hh + 1][1]);
      uh.u4[3] = pk_bf16(eh[2 * hh + 1][2], eh[2 * hh + 1][3]);
      pal[hh] = ul.v8; pah[hh] = uh.v8;
    }
    #pragma unroll
    for (int n = 0; n < 4; ++n) {
      const int dbase = (n * 16 + lr) * 64;
      #pragma unroll
      for (int hh = 0; hh < 2; ++hh) {
        const int b0 = (hh * 64 + lg * 8) ^ kx;
        const int b1 = (hh * 64 + 32 + lg * 8) ^ kx;
        union { bf16x8 v8; uint2 u2[2]; } uu;
        uu.u2[0] = *(const uint2*)&Vsh[cur][dbase + (b0 >> 1)];
        uu.u2[1] = *(const uint2*)&Vsh[cur][dbase + (b1 >> 1)];
        o_lo[n] = mfma16(pal[hh], uu.v8, o_lo[n]);
        o_hi[n] = mfma16(pah[hh], uu.v8, o_hi[n]);
      }
    }
    #pragma unroll
    for (int r = 0; r < 4; ++r) {
      float t0r = ck[r] * cd8 - sk[r] * sd8;
      sk[r] = sk[r] * cd8 + ck[r] * sd8;
      ck[r] = t0r;
    }
    __syncthreads();
    if (more) {
      const int nb = cur ^ 1;
      #pragma unroll
      for (int c = 0; c < 4; ++c) {
        int byte = (kce * 2 + c * 16) ^ ((kr & 7) << 4);
        *(uint4*)&Ksh[nb][kr * 128 + (byte >> 1)] = kreg[c];
      }
      #pragma unroll
      for (int c = 0; c < 2; ++c) {
        int byte = (vce * 2 + c * 16) ^ ((vd & 7) << 4);
        *(uint4*)&Vsh[nb][vd * 64 + (byte >> 1)] = vreg[c];
      }
      __syncthreads();
    }
  }
  // ---- epilogue: raw fp32 partials + (m,l); no normalization ----
  #pragma unroll
  for (int r = 0; r < 4; ++r) {
    const int rowL = wid * 32 + lg * 4 + r;
    #pragma unroll
    for (int n = 0; n < 4; ++n) {
      Op_my[(size_t)rowL * 64 + n * 16 + lr] = o_lo[n][r];
      Op_my[(size_t)(rowL + 16) * 64 + n * 16 + lr] = o_hi[n][r];
    }
  }
  if (lg == 0) {
    mpart[p * 128 + wid * 32 + lr] = m_lo;
    lpart[p * 128 + wid * 32 + lr] = l_lo;
    mpart[p * 128 + wid * 32 + 16 + lr] = m_hi;
    lpart[p * 128 + wid * 32 + 16 + lr] = l_hi;
  }
}

// -------- phase 2: combine 2 splits per (bh, qt) --------
// grid 512: bh=id>>4, qt=id&15. thread: row r=tid>>1, d-half d0=(tid&1)*32.
__global__ __launch_bounds__(256) void attn_comb(const float* __restrict__ Op,
                                                 const float* __restrict__ mpart,
                                                 const float* __restrict__ lpart,
                                                 ushort_t* __restrict__ O) {
  const int id = blockIdx.x;
  const int bh = id >> 4, qt = id & 15;
  const int b = bh >> 4, h = bh & 15;
  const int tid = threadIdx.x;
  const int r = tid >> 1, d0 = (tid & 1) * 32;
  const int p0 = bh * 32 + 2 * qt, p1 = p0 + 1;
  const float m0 = mpart[p0 * 128 + r], m1 = mpart[p1 * 128 + r];
  const float l0 = lpart[p0 * 128 + r], l1 = lpart[p1 * 128 + r];
  const float M = fmaxf(m0, m1);
  const float w0 = __expf(m0 - M), w1 = __expf(m1 - M);
  const float inv = 1.0f / (w0 * l0 + w1 * l1);
  const float* a0 = Op + (size_t)p0 * 8192 + (size_t)r * 64 + d0;
  const float* a1 = Op + (size_t)p1 * 8192 + (size_t)r * 64 + d0;
  unsigned po[16];
  #pragma unroll
  for (int c = 0; c < 8; ++c) {
    float4 v0 = *(const float4*)(a0 + c * 4);
    float4 v1 = *(const float4*)(a1 + c * 4);
    float o0 = (w0 * v0.x + w1 * v1.x) * inv;
    float o1 = (w0 * v0.y + w1 * v1.y) * inv;
    float o2 = (w0 * v0.z + w1 * v1.z) * inv;
    float o3 = (w0 * v0.w + w1 * v1.w) * inv;
    po[c * 2]     = (unsigned)f2bf(o0) | ((unsigned)f2bf(o1) << 16);
    po[c * 2 + 1] = (unsigned)f2bf(o2) | ((unsigned)f2bf(o3) << 16);
  }
  const int q = qt * 128 + r;
  ushort_t* dst = O + ((size_t)b * T_ + q) * C_ + h * 64 + d0;
  *(uint4*)(dst + 0)  = make_uint4(po[0], po[1], po[2], po[3]);
  *(uint4*)(dst + 8)  = make_uint4(po[4], po[5], po[6], po[7]);
  *(uint4*)(dst + 16) = make_uint4(po[8], po[9], po[10], po[11]);
  *(uint4*)(dst + 24) = make_uint4(po[12], po[13], po[14], po[15]);
}

} // namespace

extern "C" void kernel_launch(void* const* d_in, const int* in_sizes, int n_in,
                              void* d_out, int out_size, void* d_ws, size_t ws_size,
                              hipStream_t stream) {
  const float* x  = (const float*)d_in[0];
  const float* Wq = (const float*)d_in[1];
  const float* Wk = (const float*)d_in[2];
  const float* Wv = (const float*)d_in[3];
  const float* Wo = (const float*)d_in[4];
  const float* th = (const float*)d_in[5];
  float* out = (float*)d_out;
  float* ws = (float*)d_ws;

  // ---- workspace (float offsets; 22,020,096 floats = 88 MB, proven size) ----
  // Lifetimes (strictly sequential stream):
  //  Vf   [0,4194304)         : written step6, read step7; dead after.
  //  Op   [0,8388608)         : written step8 (over dead Vf), read step9.
  //  Qb   [8388608,12582912)  : written step5, read step8.
  //  Kb   [12582912,16777216) : written step5, read step8.
  //  xb   [16777216,18874368) : written step1, read steps5,6; dead after.
  //  vt   [16777216,18874368) : written step7 (over dead xb), read step8.
  //  Wqkt [18874368,20971520) : written step2, read step5; dead after.
  //  Ob   [18874368,20971520) : written step9 (over dead Wqkt), read step10.
  //  Wvt  [20971520,21495808) : written step3, read step6; dead after.
  //  mpart[20971520,21102592) : written step8 (over dead Wvt), read step9.
  //  lpart[21102592,21233664) : written step8, read step9.
  //  Wot  [21495808,22020096) : written step4, read step10.
  float* Vf  = ws;
  float* Op  = ws;
  ushort_t* Qb   = (ushort_t*)(ws + 8388608);
  ushort_t* Kb   = (ushort_t*)(ws + 12582912);
  ushort_t* xb   = (ushort_t*)(ws + 16777216);
  ushort_t* vt   = (ushort_t*)(ws + 16777216);
  ushort_t* Wqkt = (ushort_t*)(ws + 18874368);
  ushort_t* Ob   = (ushort_t*)(ws + 18874368);
  float* mpart   = ws + 20971520;
  float* lpart   = ws + 21102592;
  ushort_t* Wvt  = (ushort_t*)(ws + 20971520 + 262144);   // keep Wvt clear of m/l? no:
  // NOTE: Wvt must live where step3 writes and step6 reads, BEFORE m/l are written.
  // Place Wvt at its own slot [21233664, 21757952) to avoid any doubt.
  Wvt = (ushort_t*)(ws + 21233664);
  ushort_t* Wot  = (ushort_t*)(ws + 21757952);   // [21757952, 22020096) = 524288 bf16? 
  // Wot needs 1024*1024 bf16 = 1,048,576 elems = 524,288 floats. 21757952+524288=22282240 > ws end!
  // Revert: Wvt at [20971520,21495808) (m/l overwrite it AFTER its last read — safe),
  //         Wot at [21495808,22020096).
  Wvt = (ushort_t*)(ws + 20971520);
  Wot = (ushort_t*)(ws + 21495808);

  dim3 blk(256);
  f32_to_bf16<<<4096, blk, 0, stream>>>(x, xb);                       // 1
  wt_qk<<<dim3(32, 128), blk, 0, stream>>>(Wq, Wk, Wqkt);             // 2
  wt_bf16<<<dim3(32, 32), blk, 0, stream>>>(Wv, Wvt, 1024, 1024);     // 3
  wt_bf16<<<dim3(32, 32), blk, 0, stream>>>(Wo, Wot, 1024, 1024);     // 4
  gemm_qk<<<dim3(32, 32), blk, 0, stream>>>(xb, Wqkt, Qb, Kb, 1024);  // 5
  gemm_f32out<<<dim3(8, 32), blk, 0, stream>>>(xb, Wvt, Vf, 1024, 1024); // 6
  v_transpose<<<dim3(64, 32), blk, 0, stream>>>(Vf, vt);              // 7
  attn_split<<<1024, blk, 0, stream>>>(Qb, Kb, vt, th, Op, mpart, lpart); // 8
  attn_comb<<<512, blk, 0, stream>>>(Op, mpart, lpart, Ob);           // 9
  gemm_f32out<<<dim3(8, 32), blk, 0, stream>>>(Ob, Wot, out, 1024, 1024); // 10
}